// Round 9
// baseline (31.513 us; speedup 1.0000x reference)
//
#include <hip/hip_runtime.h>

// NQ=8, NL=3, B=65536 — fused single kernel, occupancy edition.
// Grid 1024 blocks x 256 thr; each block redundantly builds the
// sample-independent quadratic form (threads = basis j), then wave 0
// evaluates 64 samples. 4 blocks/CU co-resident -> 16 waves/CU hides the
// DPP/LDS latency chains that left R8 at 10% occupancy / 8% VALUBusy.
//   psi0_k = v0^8 * t^popcount(k), t = tan(a1/2) e^{i a2}  (rank-9 structure)
//   C = U*P (256x9, thread j holds row j = Cv[9]); final diag of U cancels.
//   G^q_i  = singleton Walsh coeffs of the 81 quadratic products -> chunked
//            in-wave WHT (<=16 floats live) + cross-wave LDS combine.
//   out_q  = q1^8 * [A^q(u) + sum_d Re(t^d) ReB^q_d(u) - Im(t^d) ImB^q_d(u)]

template <int CTRL>
__device__ __forceinline__ float dppf(float x) {
    return __int_as_float(
        __builtin_amdgcn_mov_dpp(__float_as_int(x), CTRL, 0xF, 0xF, true));
}
template <int PAT>
__device__ __forceinline__ float swzp(float x) {
    return __int_as_float(__builtin_amdgcn_ds_swizzle(__float_as_int(x), PAT));
}
// lane ^ (1<<B) exchange, cheapest primitive per bit
template <int B>
__device__ __forceinline__ float lane_xor(float x) {
    if constexpr (B == 0) return dppf<0xB1>(x);        // quad_perm xor1
    else if constexpr (B == 1) return dppf<0x4E>(x);   // quad_perm xor2
    else if constexpr (B == 2) return swzp<0x101F>(x); // ds_swizzle xor4
    else if constexpr (B == 3) return dppf<0x128>(x);  // row_ror:8 == xor8
    else if constexpr (B == 4) return swzp<0x401F>(x); // ds_swizzle xor16
    else return __shfl_xor(x, 32, 64);                 // permlane xor32
}

// Fused RY(wire0) x RY(wire1) (idx bits 7,6 — commuting gates, exact):
// one LDS round (1 barrier-pair, 3 partner reads) instead of two.
__device__ __forceinline__ void gate_lds2(float2 Cv[9], float2 (*xch)[256],
                                          float2 cs0, float2 cs1, int t) {
    __syncthreads();                       // prior xch readers done
    #pragma unroll
    for (int m = 0; m < 9; ++m) xch[m][t] = Cv[m];
    __syncthreads();
    const float s0 = (t & 128) ? cs0.y : -cs0.y;   // R[n][n^1]: +s if n=1
    const float s1 = (t & 64)  ? cs1.y : -cs1.y;
    const float a00 = cs0.x * cs1.x;   // keep both bits
    const float a01 = cs0.x * s1;      // flip bit6
    const float a10 = s0 * cs1.x;      // flip bit7
    const float a11 = s0 * s1;         // flip both
    #pragma unroll
    for (int m = 0; m < 9; ++m) {
        const float2 p01 = xch[m][t ^ 64];
        const float2 p10 = xch[m][t ^ 128];
        const float2 p11 = xch[m][t ^ 192];
        Cv[m].x = a00 * Cv[m].x + a01 * p01.x + a10 * p10.x + a11 * p11.x;
        Cv[m].y = a00 * Cv[m].y + a01 * p01.y + a10 * p10.y + a11 * p11.y;
    }
}

template <int B>
__device__ __forceinline__ void gate_wave(float2 Cv[9], float2 cs, int t) {
    const float sg = ((t >> B) & 1) ? cs.y : -cs.y;
    #pragma unroll
    for (int m = 0; m < 9; ++m) {
        const float pr = lane_xor<B>(Cv[m].x);
        const float pi = lane_xor<B>(Cv[m].y);
        Cv[m].x = cs.x * Cv[m].x + sg * pr;
        Cv[m].y = cs.x * Cv[m].y + sg * pi;
    }
}

// 6-level in-wave WHT of an N-float chunk, then store the 7 needed Walsh
// rows (this wave's lanes 0,1,2,4,8,16,32) at buf[(wv*7+row)*81 + base + i].
template <int N>
__device__ __forceinline__ void wht_chunk(float (&v)[N], float* buf,
                                          int lane, int wv, int row, int base) {
    #define WHT_LVL(B)                                                   \
    {                                                                    \
        const float sgn = ((lane >> (B)) & 1) ? -1.f : 1.f;              \
        _Pragma("unroll")                                                \
        for (int i = 0; i < N; ++i) {                                    \
            const float p = lane_xor<B>(v[i]);                           \
            v[i] = fmaf(sgn, v[i], p);                                   \
        }                                                                \
    }
    WHT_LVL(0) WHT_LVL(1) WHT_LVL(2) WHT_LVL(3) WHT_LVL(4) WHT_LVL(5)
    #undef WHT_LVL
    if (row >= 0) {
        #pragma unroll
        for (int i = 0; i < N; ++i) buf[(wv * 7 + row) * 81 + base + i] = v[i];
    }
}

// products 2 * C_{k+D} * conj(C_k), k = 0..8-D, packed re,im
template <int D, int N>
__device__ __forceinline__ void fill_pairs(const float2 (&Cv)[9], float (&c)[N],
                                           int off) {
    #pragma unroll
    for (int k = 0; k + D <= 8; ++k) {
        const float2 hi = Cv[k + D], lo = Cv[k];
        c[off + 2 * k]     = 2.f * (hi.x * lo.x + hi.y * lo.y);
        c[off + 2 * k + 1] = 2.f * (hi.y * lo.x - hi.x * lo.y);
    }
}

__global__ __launch_bounds__(256, 4)
void qsim_fused(const float* __restrict__ w, const float* __restrict__ z1,
                const float* __restrict__ z2, float* __restrict__ out,
                int nsamp) {
    __shared__ float2 xch[9][256];   // 18 KB: gate exchange; reused as WHT buf
    __shared__ float2 s_cs[3][8];    // (cos, sin) of weights[l][q]/2
    __shared__ float g[8 * 84];      // G coefficients, 84-padded rows

    const int t = threadIdx.x;
    const int lane = t & 63, wv = t >> 6;

    if (t < 24) {
        int l = t >> 3, q = t & 7;
        float a = 0.5f * w[l * 15 + q];
        s_cs[l][q] = make_float2(__cosf(a), __sinf(a));
    }
    __syncthreads();

    // ---- phase A: evolve the 9 popcount-class columns; thread = basis j = t
    float2 Cv[9];
    #pragma unroll
    for (int m = 0; m < 9; ++m)
        Cv[m] = make_float2((__popc(t) == m) ? 1.f : 0.f, 0.f);

    for (int l = 0; l < 3; ++l) {
        gate_lds2(Cv, xch, s_cs[l][0], s_cs[l][1], t);  // wires 0,1 (bits 7,6)
        gate_wave<5>(Cv, s_cs[l][2], t);
        gate_wave<4>(Cv, s_cs[l][3], t);
        gate_wave<3>(Cv, s_cs[l][4], t);
        gate_wave<2>(Cv, s_cs[l][5], t);
        gate_wave<1>(Cv, s_cs[l][6], t);
        gate_wave<0>(Cv, s_cs[l][7], t);
        if (l < 2) {                              // RZZ diag (last one cancels)
            float ang = 0.f;
            #pragma unroll
            for (int i = 0; i < 7; ++i) {
                float zz = (((t >> (7 - i)) ^ (t >> (6 - i))) & 1) ? -1.f : 1.f;
                ang = fmaf(w[l * 15 + 8 + i], zz, ang);
            }
            float s2, c2;
            __sincosf(0.5f * ang, &s2, &c2);      // amp *= exp(-0.5 i ang)
            #pragma unroll
            for (int m = 0; m < 9; ++m) {
                const float nr = Cv[m].x * c2 + Cv[m].y * s2;
                const float ni = Cv[m].y * c2 - Cv[m].x * s2;
                Cv[m].x = nr; Cv[m].y = ni;
            }
        }
    }

    // ---- phase B: chunked products + distributed WHT
    float* buf = (float*)xch;        // 4 waves * 7 rows * 81 floats = 9072 B
    __syncthreads();                 // phase-A xch readers all done
    const int row = (lane == 0) ? 0 : (lane == 1) ? 1 : (lane == 2) ? 2 :
                    (lane == 4) ? 3 : (lane == 8) ? 4 : (lane == 16) ? 5 :
                    (lane == 32) ? 6 : -1;
    {   // diag |C_m|^2  -> components 0..8
        float c[9];
        #pragma unroll
        for (int m = 0; m < 9; ++m)
            c[m] = Cv[m].x * Cv[m].x + Cv[m].y * Cv[m].y;
        wht_chunk(c, buf, lane, wv, row, 0);
    }
    { float c[16]; fill_pairs<1>(Cv, c, 0); wht_chunk(c, buf, lane, wv, row, 9);  }
    { float c[14]; fill_pairs<2>(Cv, c, 0); wht_chunk(c, buf, lane, wv, row, 25); }
    { float c[12]; fill_pairs<3>(Cv, c, 0); wht_chunk(c, buf, lane, wv, row, 39); }
    { float c[10]; fill_pairs<4>(Cv, c, 0); wht_chunk(c, buf, lane, wv, row, 51); }
    { float c[8];  fill_pairs<5>(Cv, c, 0); wht_chunk(c, buf, lane, wv, row, 61); }
    {   // d = 6,7,8 combined -> components 69..80
        float c[12];
        fill_pairs<6>(Cv, c, 0);
        fill_pairs<7>(Cv, c, 6);
        fill_pairs<8>(Cv, c, 10);
        wht_chunk(c, buf, lane, wv, row, 69);
    }
    __syncthreads();
    // cross-wave combine; qubit q <-> idx bit b = 7-q
    for (int o = t; o < 648; o += 256) {
        const int q = o / 81, i = o - 81 * q;
        const int b = 7 - q;
        float r;
        if (b < 6) {                              // Walsh index 2^b: all waves +
            const int rw = b + 1;
            r = buf[(0 * 7 + rw) * 81 + i] + buf[(1 * 7 + rw) * 81 + i] +
                buf[(2 * 7 + rw) * 81 + i] + buf[(3 * 7 + rw) * 81 + i];
        } else if (b == 6) {                      // sign = (-1)^{bit0(wave)}
            r = buf[(0 * 7) * 81 + i] - buf[(1 * 7) * 81 + i] +
                buf[(2 * 7) * 81 + i] - buf[(3 * 7) * 81 + i];
        } else {                                  // sign = (-1)^{bit1(wave)}
            r = buf[(0 * 7) * 81 + i] + buf[(1 * 7) * 81 + i] -
                buf[(2 * 7) * 81 + i] - buf[(3 * 7) * 81 + i];
        }
        g[q * 84 + i] = r;
    }
    __syncthreads();

    // ---- phase C: wave 0 evaluates this block's 64 samples (1 per lane);
    // waves 1..3 retire, freeing their SIMDs for other blocks' preludes.
    const int s = blockIdx.x * 64 + t;
    if (t >= 64 || s >= nsamp) return;

    const float z1v = z1[s], z2v = z2[s];
    const float u1 = sqrtf(fmaxf(0.f, 1.f - z1v * z1v));   // cos a1
    const float q1 = 0.5f * (1.f + u1);                     // cos^2(a1/2)
    const float s1 = copysignf(sqrtf(fmaxf(0.f, 0.5f * (1.f - u1))), z1v);
    const float tn = s1 * rsqrtf(q1);                       // tan(a1/2)
    const float u2 = sqrtf(fmaxf(0.f, 1.f - z2v * z2v));    // cos a2
    const float tr = tn * u2, ti = tn * z2v;                // t = tn e^{i a2}
    const float u  = tn * tn;                               // |t|^2
    float w8 = q1 * q1; w8 *= w8; w8 *= w8;                 // q1^8

    float Tr[9], Ti[9];
    Tr[1] = tr; Ti[1] = ti;
    #pragma unroll
    for (int d = 2; d <= 8; ++d) {
        Tr[d] = Tr[d - 1] * tr - Ti[d - 1] * ti;
        Ti[d] = Tr[d - 1] * ti + Ti[d - 1] * tr;
    }

    float o[8];
    #pragma unroll
    for (int q = 0; q < 8; ++q) {
        const float* gq = g + q * 84;            // LDS, broadcast reads
        float r = gq[8];
        #pragma unroll
        for (int m = 7; m >= 0; --m) r = fmaf(r, u, gq[m]);
        int off = 9;
        #pragma unroll
        for (int d = 1; d <= 8; ++d) {
            const int K = 8 - d;                 // poly degree in u
            float br = gq[off + 2 * K], bi = gq[off + 2 * K + 1];
            #pragma unroll
            for (int k = K - 1; k >= 0; --k) {
                br = fmaf(br, u, gq[off + 2 * k]);
                bi = fmaf(bi, u, gq[off + 2 * k + 1]);
            }
            r = fmaf(Tr[d], br, r);
            r = fmaf(-Ti[d], bi, r);
            off += 2 * (K + 1);
        }
        o[q] = w8 * r;
    }

    float4* op = (float4*)(out + (size_t)s * 8);
    op[0] = make_float4(o[0], o[1], o[2], o[3]);
    op[1] = make_float4(o[4], o[5], o[6], o[7]);
}

extern "C" void kernel_launch(void* const* d_in, const int* in_sizes, int n_in,
                              void* d_out, int out_size, void* d_ws,
                              size_t ws_size, hipStream_t stream) {
    const float* w  = (const float*)d_in[0];   // (3, 15) f32
    const float* z1 = (const float*)d_in[1];   // (B,)   f32
    const float* z2 = (const float*)d_in[2];   // (B,)   f32
    float* out = (float*)d_out;                // (B, 8) f32

    const int n = in_sizes[1];
    qsim_fused<<<(n + 63) / 64, 256, 0, stream>>>(w, z1, z2, out, n);
}

// Round 10
// 17.903 us; speedup vs baseline: 1.7602x; 1.7602x over previous
//
#include <hip/hip_runtime.h>

// NQ=8, NL=3, B=65536 — fused single kernel, split-prelude edition.
// Grid 256 blocks x 512 thr. Each block: threads (j = t&255, h = t>>8).
// Phase A: thread (j,h) evolves 5 of the 9 popcount-class columns
//   (h=0: cols 0-4, h=1: cols 4-8; col 4 duplicated -> identical LDS writes).
// Phase B: restage full row C_j via LDS; group h WHTs ~half of the 81
//   quadratic products (6 in-wave levels + cross-wave LDS combine).
// Phase C: threads t<256 evaluate one sample each (prep hoisted to kernel
//   top so z-load latency hides under phase A).
// Total chip-wide prelude work == R8 (256 copies), critical path ~halved,
// 2 waves/SIMD instead of 1.

template <int CTRL>
__device__ __forceinline__ float dppf(float x) {
    return __int_as_float(
        __builtin_amdgcn_mov_dpp(__float_as_int(x), CTRL, 0xF, 0xF, true));
}
template <int PAT>
__device__ __forceinline__ float swzp(float x) {
    return __int_as_float(__builtin_amdgcn_ds_swizzle(__float_as_int(x), PAT));
}
// lane ^ (1<<B) exchange, cheapest primitive per bit
template <int B>
__device__ __forceinline__ float lane_xor(float x) {
    if constexpr (B == 0) return dppf<0xB1>(x);        // quad_perm xor1
    else if constexpr (B == 1) return dppf<0x4E>(x);   // quad_perm xor2
    else if constexpr (B == 2) return swzp<0x101F>(x); // ds_swizzle xor4
    else if constexpr (B == 3) return dppf<0x128>(x);  // row_ror:8 == xor8
    else if constexpr (B == 4) return swzp<0x401F>(x); // ds_swizzle xor16
    else return __shfl_xor(x, 32, 64);                 // xor32
}

// Fused RY(wire0) x RY(wire1) on j bits 7,6 — one LDS round, 5 columns.
__device__ __forceinline__ void gate_lds2_5(float2 Cv[5], float2 (*xch)[256],
                                            float2 cs0, float2 cs1,
                                            int j, int M0) {
    __syncthreads();                       // prior xch readers done
    #pragma unroll
    for (int m = 0; m < 5; ++m) xch[M0 + m][j] = Cv[m];
    __syncthreads();
    const float s0 = (j & 128) ? cs0.y : -cs0.y;
    const float s1 = (j & 64)  ? cs1.y : -cs1.y;
    const float a00 = cs0.x * cs1.x;
    const float a01 = cs0.x * s1;
    const float a10 = s0 * cs1.x;
    const float a11 = s0 * s1;
    #pragma unroll
    for (int m = 0; m < 5; ++m) {
        const float2 p01 = xch[M0 + m][j ^ 64];
        const float2 p10 = xch[M0 + m][j ^ 128];
        const float2 p11 = xch[M0 + m][j ^ 192];
        Cv[m].x = a00 * Cv[m].x + a01 * p01.x + a10 * p10.x + a11 * p11.x;
        Cv[m].y = a00 * Cv[m].y + a01 * p01.y + a10 * p10.y + a11 * p11.y;
    }
}

template <int B>
__device__ __forceinline__ void gate_wave5(float2 Cv[5], float2 cs, int j) {
    const float sg = ((j >> B) & 1) ? cs.y : -cs.y;
    #pragma unroll
    for (int m = 0; m < 5; ++m) {
        const float pr = lane_xor<B>(Cv[m].x);
        const float pi = lane_xor<B>(Cv[m].y);
        Cv[m].x = cs.x * Cv[m].x + sg * pr;
        Cv[m].y = cs.x * Cv[m].y + sg * pi;
    }
}

// 6-level in-wave WHT of an N-float chunk; store the 7 needed Walsh rows
// (this wave's lanes 0,1,2,4,8,16,32) at buf[(wvg*7+row)*81 + base + i].
template <int N>
__device__ __forceinline__ void wht_chunk(float (&v)[N], float* buf,
                                          int lane, int wvg, int row, int base) {
    #define WHT_LVL(B)                                                   \
    {                                                                    \
        const float sgn = ((lane >> (B)) & 1) ? -1.f : 1.f;              \
        _Pragma("unroll")                                                \
        for (int i = 0; i < N; ++i) {                                    \
            const float p = lane_xor<B>(v[i]);                           \
            v[i] = fmaf(sgn, v[i], p);                                   \
        }                                                                \
    }
    WHT_LVL(0) WHT_LVL(1) WHT_LVL(2) WHT_LVL(3) WHT_LVL(4) WHT_LVL(5)
    #undef WHT_LVL
    if (row >= 0) {
        #pragma unroll
        for (int i = 0; i < N; ++i) buf[(wvg * 7 + row) * 81 + base + i] = v[i];
    }
}

// products 2 * C_{k+D} * conj(C_k), k = 0..8-D, packed re,im
template <int D, int N>
__device__ __forceinline__ void fill_pairs(const float2 (&C9)[9], float (&c)[N],
                                           int off) {
    #pragma unroll
    for (int k = 0; k + D <= 8; ++k) {
        const float2 hi = C9[k + D], lo = C9[k];
        c[off + 2 * k]     = 2.f * (hi.x * lo.x + hi.y * lo.y);
        c[off + 2 * k + 1] = 2.f * (hi.y * lo.x - hi.x * lo.y);
    }
}

__global__ __launch_bounds__(512, 2)
void qsim_fused(const float* __restrict__ w, const float* __restrict__ z1,
                const float* __restrict__ z2, float* __restrict__ out,
                int nsamp) {
    __shared__ float2 xch[9][256];   // 18 KB: gate exchange; reused as WHT buf
    __shared__ float2 s_cs[3][8];    // (cos, sin) of weights[l][q]/2
    __shared__ float g[8 * 84];      // G coefficients, 84-padded rows

    const int t = threadIdx.x;
    const int j = t & 255;           // basis index
    const int h = t >> 8;            // column/component group
    const int M0 = h * 4;            // first owned column
    const int lane = t & 63, wvg = (t >> 6) & 3;

    // ---- phase C prep hoisted: z-load latency hides under phase A
    const int s = blockIdx.x * 256 + t;
    const bool do_eval = (t < 256) && (s < nsamp);
    float Tr[9], Ti[9], u = 0.f, w8 = 0.f;
    if (do_eval) {
        const float z1v = z1[s], z2v = z2[s];
        const float u1 = sqrtf(fmaxf(0.f, 1.f - z1v * z1v));   // cos a1
        const float q1 = 0.5f * (1.f + u1);                     // cos^2(a1/2)
        const float s1 = copysignf(sqrtf(fmaxf(0.f, 0.5f * (1.f - u1))), z1v);
        const float tn = s1 * rsqrtf(q1);                       // tan(a1/2)
        const float u2 = sqrtf(fmaxf(0.f, 1.f - z2v * z2v));    // cos a2
        const float tr = tn * u2, ti = tn * z2v;                // t = tn e^{i a2}
        u = tn * tn;
        w8 = q1 * q1; w8 *= w8; w8 *= w8;                       // q1^8
        Tr[1] = tr; Ti[1] = ti;
        #pragma unroll
        for (int d = 2; d <= 8; ++d) {
            Tr[d] = Tr[d - 1] * tr - Ti[d - 1] * ti;
            Ti[d] = Tr[d - 1] * ti + Ti[d - 1] * tr;
        }
    }

    if (t < 24) {
        int l = t >> 3, q = t & 7;
        float a = 0.5f * w[l * 15 + q];
        s_cs[l][q] = make_float2(__cosf(a), __sinf(a));
    }
    __syncthreads();

    // ---- phase A: evolve 5 owned columns; thread-pair (j,0/1) covers 9
    float2 Cv[5];
    #pragma unroll
    for (int m = 0; m < 5; ++m)
        Cv[m] = make_float2((__popc(j) == M0 + m) ? 1.f : 0.f, 0.f);

    for (int l = 0; l < 3; ++l) {
        gate_lds2_5(Cv, xch, s_cs[l][0], s_cs[l][1], j, M0);  // bits 7,6
        gate_wave5<5>(Cv, s_cs[l][2], j);
        gate_wave5<4>(Cv, s_cs[l][3], j);
        gate_wave5<3>(Cv, s_cs[l][4], j);
        gate_wave5<2>(Cv, s_cs[l][5], j);
        gate_wave5<1>(Cv, s_cs[l][6], j);
        gate_wave5<0>(Cv, s_cs[l][7], j);
        if (l < 2) {                              // RZZ diag (last one cancels)
            float ang = 0.f;
            #pragma unroll
            for (int i = 0; i < 7; ++i) {
                float zz = (((j >> (7 - i)) ^ (j >> (6 - i))) & 1) ? -1.f : 1.f;
                ang = fmaf(w[l * 15 + 8 + i], zz, ang);
            }
            float s2, c2;
            __sincosf(0.5f * ang, &s2, &c2);      // amp *= exp(-0.5 i ang)
            #pragma unroll
            for (int m = 0; m < 5; ++m) {
                const float nr = Cv[m].x * c2 + Cv[m].y * s2;
                const float ni = Cv[m].y * c2 - Cv[m].x * s2;
                Cv[m].x = nr; Cv[m].y = ni;
            }
        }
    }

    // ---- restage: every thread gets the full row C_j (9 columns)
    __syncthreads();                 // layer-2 gate_lds2 readers done
    #pragma unroll
    for (int m = 0; m < 5; ++m) xch[M0 + m][j] = Cv[m];
    __syncthreads();
    float2 C9[9];
    #pragma unroll
    for (int m = 0; m < 9; ++m) C9[m] = xch[m][j];
    __syncthreads();                 // all reads done before buf overwrite

    // ---- phase B: group h WHTs its component subset
    float* buf = (float*)xch + h * (28 * 81);   // 2 * 28*81 floats < 18 KB
    const int row = (lane == 0) ? 0 : (lane == 1) ? 1 : (lane == 2) ? 2 :
                    (lane == 4) ? 3 : (lane == 8) ? 4 : (lane == 16) ? 5 :
                    (lane == 32) ? 6 : -1;
    if (h == 0) {                    // components 0..38: diag, d=1, d=2
        {   float c[9];
            #pragma unroll
            for (int m = 0; m < 9; ++m)
                c[m] = C9[m].x * C9[m].x + C9[m].y * C9[m].y;
            wht_chunk(c, buf, lane, wvg, row, 0);
        }
        { float c[16]; fill_pairs<1>(C9, c, 0); wht_chunk(c, buf, lane, wvg, row, 9);  }
        { float c[14]; fill_pairs<2>(C9, c, 0); wht_chunk(c, buf, lane, wvg, row, 25); }
    } else {                         // components 39..80: d=3..8
        { float c[12]; fill_pairs<3>(C9, c, 0); wht_chunk(c, buf, lane, wvg, row, 39); }
        { float c[10]; fill_pairs<4>(C9, c, 0); wht_chunk(c, buf, lane, wvg, row, 51); }
        { float c[8];  fill_pairs<5>(C9, c, 0); wht_chunk(c, buf, lane, wvg, row, 61); }
        {   float c[12];
            fill_pairs<6>(C9, c, 0);
            fill_pairs<7>(C9, c, 6);
            fill_pairs<8>(C9, c, 10);
            wht_chunk(c, buf, lane, wvg, row, 69);
        }
    }
    __syncthreads();
    // cross-wave combine; qubit q <-> idx bit b = 7-q
    for (int o = t; o < 648; o += 512) {
        const int q = o / 81, i = o - 81 * q;
        const int b = 7 - q;
        const float* gb = (const float*)xch + ((i < 39) ? 0 : 28 * 81);
        float r;
        if (b < 6) {                              // Walsh index 2^b: all waves +
            const int rw = b + 1;
            r = gb[(0 * 7 + rw) * 81 + i] + gb[(1 * 7 + rw) * 81 + i] +
                gb[(2 * 7 + rw) * 81 + i] + gb[(3 * 7 + rw) * 81 + i];
        } else if (b == 6) {                      // sign = (-1)^{bit0(wave)}
            r = gb[(0 * 7) * 81 + i] - gb[(1 * 7) * 81 + i] +
                gb[(2 * 7) * 81 + i] - gb[(3 * 7) * 81 + i];
        } else {                                  // sign = (-1)^{bit1(wave)}
            r = gb[(0 * 7) * 81 + i] + gb[(1 * 7) * 81 + i] -
                gb[(2 * 7) * 81 + i] - gb[(3 * 7) * 81 + i];
        }
        g[q * 84 + i] = r;
    }
    __syncthreads();

    // ---- phase C: threads 0..255 evaluate one sample each
    if (!do_eval) return;

    float o[8];
    #pragma unroll
    for (int q = 0; q < 8; ++q) {
        const float* gq = g + q * 84;            // LDS, broadcast reads
        float r = gq[8];
        #pragma unroll
        for (int m = 7; m >= 0; --m) r = fmaf(r, u, gq[m]);
        int off = 9;
        #pragma unroll
        for (int d = 1; d <= 8; ++d) {
            const int K = 8 - d;                 // poly degree in u
            float br = gq[off + 2 * K], bi = gq[off + 2 * K + 1];
            #pragma unroll
            for (int k = K - 1; k >= 0; --k) {
                br = fmaf(br, u, gq[off + 2 * k]);
                bi = fmaf(bi, u, gq[off + 2 * k + 1]);
            }
            r = fmaf(Tr[d], br, r);
            r = fmaf(-Ti[d], bi, r);
            off += 2 * (K + 1);
        }
        o[q] = w8 * r;
    }

    float4* op = (float4*)(out + (size_t)s * 8);
    op[0] = make_float4(o[0], o[1], o[2], o[3]);
    op[1] = make_float4(o[4], o[5], o[6], o[7]);
}

extern "C" void kernel_launch(void* const* d_in, const int* in_sizes, int n_in,
                              void* d_out, int out_size, void* d_ws,
                              size_t ws_size, hipStream_t stream) {
    const float* w  = (const float*)d_in[0];   // (3, 15) f32
    const float* z1 = (const float*)d_in[1];   // (B,)   f32
    const float* z2 = (const float*)d_in[2];   // (B,)   f32
    float* out = (float*)d_out;                // (B, 8) f32

    const int n = in_sizes[1];
    qsim_fused<<<(n + 255) / 256, 512, 0, stream>>>(w, z1, z2, out, n);
}